// Round 5
// baseline (387.411 us; speedup 1.0000x reference)
//
#include <hip/hip_runtime.h>
#include <hip/hip_bf16.h>
#include <cstdint>

typedef __bf16 bf16;
typedef __bf16 bf16x8 __attribute__((ext_vector_type(8)));
typedef __bf16 bf16x4 __attribute__((ext_vector_type(4)));
typedef __bf16 bf16x2 __attribute__((ext_vector_type(2)));
typedef float floatx4 __attribute__((ext_vector_type(4)));
typedef float f32x16 __attribute__((ext_vector_type(16)));
typedef int intx4 __attribute__((ext_vector_type(4)));

#define MFMA16(a, b, c) __builtin_amdgcn_mfma_f32_16x16x32_bf16(a, b, c, 0, 0, 0)
#define MFMA32(a, b, c) __builtin_amdgcn_mfma_f32_32x32x16_bf16(a, b, c, 0, 0, 0)

__device__ __forceinline__ void gload_lds16(const void* g, void* l) {
    __builtin_amdgcn_global_load_lds(
        (const __attribute__((address_space(1))) void*)g,
        (__attribute__((address_space(3))) void*)l, 16, 0, 0);
}

// Raw barrier (no vmcnt/lgkm drain) + explicit counted waits.
#define BARRIER()     asm volatile("s_barrier" ::: "memory")
#define WAIT_LGKM0()  do { asm volatile("s_waitcnt lgkmcnt(0)" ::: "memory"); \
                           __builtin_amdgcn_sched_barrier(0); } while (0)
#define WAIT_VM(N)    asm volatile("s_waitcnt vmcnt(" #N ")" ::: "memory")

__device__ __forceinline__ int pack2(float a, float b) {
    union { bf16x2 v; int u; } z;
    z.v[0] = (bf16)a;
    z.v[1] = (bf16)b;
    return z.u;
}

// ---------------------------------------------------------------------------
// Fused prep: one launch does fp32->bf16 downcast of x AND both weight
// transposes (block-range dispatch). Bodies identical to the previous three
// kernels; saves 2 kernel launches of gap overhead.
//   blocks [0, 8192):          downcast x -> xb
//   blocks [8192, 20480):      transpose Wqkv [2048][6144] -> WqkvT
//   blocks [20480, 24576):     transpose Wo   [2048][2048] -> WoT
// ---------------------------------------------------------------------------
__global__ __launch_bounds__(256) void prep_kernel(
    const float* __restrict__ x, const float* __restrict__ Wqkv,
    const float* __restrict__ Wo, bf16* __restrict__ xb,
    bf16* __restrict__ WqkvT, bf16* __restrict__ WoT) {
    __shared__ float tile[32][33];
    const int bid = blockIdx.x;
    const int tid = threadIdx.x;

    if (bid < 8192) {
        const size_t i = ((size_t)bid * 256 + tid) * 4;
        const float4 v = *(const float4*)(x + i);
        bf16x4 o = {(bf16)v.x, (bf16)v.y, (bf16)v.z, (bf16)v.w};
        *(bf16x4*)(xb + i) = o;
        return;
    }

    const float* in;
    bf16* out;
    int R, C, bx, by;
    if (bid < 20480) {
        const int b = bid - 8192;
        in = Wqkv; out = WqkvT; R = 2048; C = 6144;
        bx = b % 192; by = b / 192;
    } else {
        const int b = bid - 20480;
        in = Wo; out = WoT; R = 2048; C = 2048;
        bx = b & 63; by = b >> 6;
    }
    const int c0 = bx * 32, r0 = by * 32;
    const int tx = tid & 31, ty = tid >> 5;
    for (int i = 0; i < 32; i += 8)
        tile[ty + i][tx] = in[(size_t)(r0 + ty + i) * C + (c0 + tx)];
    __syncthreads();
    for (int i = 0; i < 32; i += 8)
        out[(size_t)(c0 + ty + i) * R + (r0 + tx)] = (bf16)tile[tx][ty + i];
}

// ---------------------------------------------------------------------------
// 8-phase 256x256 qkv GEMM, v2 (R1 post-mortem fixes).
// C[M=4096][N=6144] = A@BT^T, K=2048; epilogue scatters q/k/v.
//
// Geometry: BM=BN=256, BK=64, 512 thr = 8 waves (2M x 4N), per-wave C 128x64
// = acc[8][4]. LDS 128 KiB double-buffered. Swizzle: verified 16B-seg XOR
// (seg = sp ^ (row&7)), 0 bank conflicts in R0-R4.
//
// Key structural fact: each wave reads exactly ONE A-half (wm) and ONE
// B-half (wn) of the 256-row tiles, and quadrant Q3 needs NO ds_reads
// (frags cached from Q0-Q2). So:
//   ph0 (Q0 = Mlo x Nlo): read alo(8 b128) + blo(4)    | 16 MFMA
//   ph1 (Q1 = Mlo x Nhi): read bhi(4)                  | 16 MFMA
//   ph2 (Q2 = Mhi x Nhi): read ahi(8)                  | 16 MFMA
//   ph3 (Q3 = Mhi x Nlo): NO reads; stage ALL of tile t+2 (8 gload)
//                         into buf[t&1] (WAR-safe: ph2-end barrier separates
//                         the last read of buf[t&1] from ph3's stage issue)
//                         | 16 MFMA | vmcnt(8) | barrier
// Counted vmcnt(8) at tile end: tile t+1's batch (oldest 8) landed, tile
// t+2's batch (newest 8) stays in flight across the whole next tile
// (~1200 cyc > 900 cyc HBM miss). Never drained to 0 in the main loop (T4).
// Each phase: reads -> barrier -> lgkmcnt(0)+sched_barrier(0) [rule 18] ->
// setprio(1) 16 MFMA setprio(0) -> barrier.
// Grid 24x16 = 384 blocks (1.5 rounds at 1 block/CU), bijective XCD swizzle.
// ---------------------------------------------------------------------------
__global__ __launch_bounds__(512, 1) void gemm256_qkv_kernel(
    const bf16* __restrict__ A, const bf16* __restrict__ BT, int K,
    bf16* __restrict__ qt, bf16* __restrict__ kt, bf16* __restrict__ vt) {
    __shared__ alignas(16) bf16 As[2][16384];  // 64 KB
    __shared__ alignas(16) bf16 Bs[2][16384];  // 64 KB

    const int tid = threadIdx.x;
    const int wave = tid >> 6, lane = tid & 63;
    const int quad = lane >> 4, r16 = lane & 15;

    const int flat = blockIdx.y * 24 + blockIdx.x;
    const int swz = (flat & 7) * 48 + (flat >> 3);  // 384 % 8 == 0: bijective
    const int n0 = (swz % 24) << 8, m0 = (swz / 24) << 8;

    const int wm = (wave >> 2) << 7;  // 0 or 128
    const int wn = (wave & 3) << 6;   // 0,64,128,192

    // stage the complete K-tile kt_ (A h0,h1 + B h0,h1 = 8 gload/thread)
    auto stageTile = [&](int buf, int kt_) {
#pragma unroll
        for (int hf = 0; hf < 2; ++hf)
#pragma unroll
            for (int j = 0; j < 2; ++j) {
                const int c = tid + j * 512;
                const int row = c >> 3;
                const int soff = ((c & 7) ^ (row & 7)) * 8;
                gload_lds16(A + (size_t)(m0 + hf * 128 + row) * K + kt_ * 64 + soff,
                            &As[buf][hf * 8192 + c * 8]);
            }
#pragma unroll
        for (int hf = 0; hf < 2; ++hf)
#pragma unroll
            for (int j = 0; j < 2; ++j) {
                const int c = tid + j * 512;
                const int row = c >> 3;
                const int soff = ((c & 7) ^ (row & 7)) * 8;
                gload_lds16(BT + (size_t)(n0 + hf * 128 + row) * K + kt_ * 64 + soff,
                            &Bs[buf][hf * 8192 + c * 8]);
            }
    };

    floatx4 acc[8][4] = {};
    const int NT = K >> 6;  // 32

    // prologue: tile0 -> buf0, tile1 -> buf1; wait tile0 only (counted).
    stageTile(0, 0);
    stageTile(1, 1);
    WAIT_VM(8);
    BARRIER();

    for (int t = 0; t < NT; ++t) {
        const int bsel = t & 1;
        const bf16* Ab = &As[bsel][0];
        const bf16* Bb = &Bs[bsel][0];
        bf16x8 alo[4][2], ahi[4][2], blo[2][2], bhi[2][2];

        // ---- ph0: Q0 (Mlo x Nlo), read alo+blo ----------------------------
#pragma unroll
        for (int i = 0; i < 4; ++i) {
            const int row = wm + i * 16 + r16;
#pragma unroll
            for (int kc = 0; kc < 2; ++kc)
                alo[i][kc] = *(const bf16x8*)(Ab + row * 64 + (((4 * kc + quad) ^ (row & 7)) << 3));
        }
#pragma unroll
        for (int j = 0; j < 2; ++j) {
            const int row = wn + j * 16 + r16;
#pragma unroll
            for (int kc = 0; kc < 2; ++kc)
                blo[j][kc] = *(const bf16x8*)(Bb + row * 64 + (((4 * kc + quad) ^ (row & 7)) << 3));
        }
        BARRIER();
        WAIT_LGKM0();
        __builtin_amdgcn_s_setprio(1);
#pragma unroll
        for (int i = 0; i < 4; ++i)
#pragma unroll
            for (int j = 0; j < 2; ++j)
#pragma unroll
                for (int kc = 0; kc < 2; ++kc)
                    acc[i][j] = MFMA16(alo[i][kc], blo[j][kc], acc[i][j]);
        __builtin_amdgcn_s_setprio(0);
        BARRIER();

        // ---- ph1: Q1 (Mlo x Nhi), read bhi --------------------------------
#pragma unroll
        for (int j = 0; j < 2; ++j) {
            const int row = wn + (2 + j) * 16 + r16;
#pragma unroll
            for (int kc = 0; kc < 2; ++kc)
                bhi[j][kc] = *(const bf16x8*)(Bb + row * 64 + (((4 * kc + quad) ^ (row & 7)) << 3));
        }
        BARRIER();
        WAIT_LGKM0();
        __builtin_amdgcn_s_setprio(1);
#pragma unroll
        for (int i = 0; i < 4; ++i)
#pragma unroll
            for (int j = 0; j < 2; ++j)
#pragma unroll
                for (int kc = 0; kc < 2; ++kc)
                    acc[i][2 + j] = MFMA16(alo[i][kc], bhi[j][kc], acc[i][2 + j]);
        __builtin_amdgcn_s_setprio(0);
        BARRIER();

        // ---- ph2: Q2 (Mhi x Nhi), read ahi --------------------------------
#pragma unroll
        for (int i = 0; i < 4; ++i) {
            const int row = wm + (4 + i) * 16 + r16;
#pragma unroll
            for (int kc = 0; kc < 2; ++kc)
                ahi[i][kc] = *(const bf16x8*)(Ab + row * 64 + (((4 * kc + quad) ^ (row & 7)) << 3));
        }
        BARRIER();
        WAIT_LGKM0();
        __builtin_amdgcn_s_setprio(1);
#pragma unroll
        for (int i = 0; i < 4; ++i)
#pragma unroll
            for (int j = 0; j < 2; ++j)
#pragma unroll
                for (int kc = 0; kc < 2; ++kc)
                    acc[4 + i][2 + j] = MFMA16(ahi[i][kc], bhi[j][kc], acc[4 + i][2 + j]);
        __builtin_amdgcn_s_setprio(0);
        BARRIER();

        // ---- ph3: Q3 (Mhi x Nlo), NO reads; stage tile t+2 ----------------
        if (t + 2 < NT) stageTile(bsel, t + 2);
        __builtin_amdgcn_s_setprio(1);
#pragma unroll
        for (int i = 0; i < 4; ++i)
#pragma unroll
            for (int j = 0; j < 2; ++j)
#pragma unroll
                for (int kc = 0; kc < 2; ++kc)
                    acc[4 + i][j] = MFMA16(ahi[i][kc], blo[j][kc], acc[4 + i][j]);
        __builtin_amdgcn_s_setprio(0);
        if (t + 2 < NT) WAIT_VM(8);   // t+1 landed; t+2 stays in flight
        else           WAIT_VM(0);    // epilogue drain (cheap, loads are old)
        BARRIER();
    }

    // ---- epilogue: scatter to q/k/v (verified mapping) ---------------------
    const int tsel = n0 >> 11;
    const float qscale = 0.08838834764831845f;  // 128^-0.5
#pragma unroll
    for (int i = 0; i < 8; ++i) {
        const int mbase = m0 + wm + i * 16 + quad * 4;
        const int b_ = mbase >> 11;
        const int s = mbase & 2047;
#pragma unroll
        for (int j = 0; j < 4; ++j) {
            const int n = n0 + wn + j * 16 + r16;
            const int h = (n >> 7) & 15, hd = n & 127;
            const int bh = b_ * 16 + h;
            if (tsel == 0) {
#pragma unroll
                for (int r = 0; r < 4; ++r)
                    qt[(size_t)(bh * 2048 + s + r) * 128 + hd] =
                        (bf16)(acc[i][j][r] * qscale);
            } else if (tsel == 1) {
#pragma unroll
                for (int r = 0; r < 4; ++r)
                    kt[(size_t)(bh * 2048 + s + r) * 128 + hd] = (bf16)acc[i][j][r];
            } else {
                bf16x4 pv = {(bf16)acc[i][j][0], (bf16)acc[i][j][1],
                             (bf16)acc[i][j][2], (bf16)acc[i][j][3]};
                *(bf16x4*)(vt + (size_t)(bh * 128 + hd) * 2048 + s) = pv;
            }
        }
    }
}

// ---------------------------------------------------------------------------
// GEMM: C[M][N] = A[M][K] @ BT[N][K]^T   (bf16 in, fp32 accum)
// Verified 128x128 m97-structure; used for the Wo projection (MODE 1).
// ---------------------------------------------------------------------------
template <int MODE>
__global__ __launch_bounds__(256) void gemm_bt_kernel(
    const bf16* __restrict__ A, const bf16* __restrict__ BT,
    int M, int N, int K,
    bf16* __restrict__ qt, bf16* __restrict__ kt, bf16* __restrict__ vt,
    float* __restrict__ Cout) {
    __shared__ alignas(16) bf16 As[128 * 64];  // 16 KB
    __shared__ alignas(16) bf16 Bs[128 * 64];  // 16 KB

    const int tid = threadIdx.x;
    const int wave = tid >> 6, lane = tid & 63;
    const int quad = lane >> 4, r16 = lane & 15;
    const int m0 = blockIdx.y * 128, n0 = blockIdx.x * 128;
    const int wm = (wave >> 1) * 64, wn = (wave & 1) * 64;

    int srow[4], soff[4];
#pragma unroll
    for (int j = 0; j < 4; ++j) {
        const int c = tid + j * 256;
        srow[j] = c >> 3;
        soff[j] = ((c & 7) ^ (srow[j] & 7)) * 8;
    }

    floatx4 acc[4][4] = {};

    for (int k0 = 0; k0 < K; k0 += 64) {
        __syncthreads();
#pragma unroll
        for (int j = 0; j < 4; ++j) {
            const int c = tid + j * 256;
            gload_lds16(A + (size_t)(m0 + srow[j]) * K + k0 + soff[j], As + c * 8);
            gload_lds16(BT + (size_t)(n0 + srow[j]) * K + k0 + soff[j], Bs + c * 8);
        }
        __syncthreads();

#pragma unroll
        for (int kc = 0; kc < 2; ++kc) {
            bf16x8 a[4], b[4];
#pragma unroll
            for (int i = 0; i < 4; ++i) {
                const int row = wm + i * 16 + r16;
                const int sp = (4 * kc + quad) ^ (row & 7);
                a[i] = *(const bf16x8*)(As + row * 64 + sp * 8);
            }
#pragma unroll
            for (int j = 0; j < 4; ++j) {
                const int row = wn + j * 16 + r16;
                const int sp = (4 * kc + quad) ^ (row & 7);
                b[j] = *(const bf16x8*)(Bs + row * 64 + sp * 8);
            }
#pragma unroll
            for (int i = 0; i < 4; ++i)
#pragma unroll
                for (int j = 0; j < 4; ++j)
                    acc[i][j] = MFMA16(a[i], b[j], acc[i][j]);
        }
    }

    if (MODE == 0) {
        const int t = n0 >> 11;
        const float qscale = 0.08838834764831845f;
#pragma unroll
        for (int i = 0; i < 4; ++i) {
            const int mbase = m0 + wm + i * 16 + quad * 4;
            const int b_ = mbase >> 11;
            const int s = mbase & 2047;
#pragma unroll
            for (int j = 0; j < 4; ++j) {
                const int n = n0 + wn + j * 16 + r16;
                const int h = (n >> 7) & 15, hd = n & 127;
                const int bh = b_ * 16 + h;
                if (t == 0) {
#pragma unroll
                    for (int r = 0; r < 4; ++r)
                        qt[(size_t)(bh * 2048 + s + r) * 128 + hd] =
                            (bf16)(acc[i][j][r] * qscale);
                } else if (t == 1) {
#pragma unroll
                    for (int r = 0; r < 4; ++r)
                        kt[(size_t)(bh * 2048 + s + r) * 128 + hd] = (bf16)acc[i][j][r];
                } else {
                    bf16x4 pv = {(bf16)acc[i][j][0], (bf16)acc[i][j][1],
                                 (bf16)acc[i][j][2], (bf16)acc[i][j][3]};
                    *(bf16x4*)(vt + (size_t)(bh * 128 + hd) * 2048 + s) = pv;
                }
            }
        }
    } else {
#pragma unroll
        for (int i = 0; i < 4; ++i) {
            const int mbase = m0 + wm + i * 16 + quad * 4;
#pragma unroll
            for (int j = 0; j < 4; ++j) {
                const int n = n0 + wn + j * 16 + r16;
#pragma unroll
                for (int r = 0; r < 4; ++r)
                    Cout[(size_t)(mbase + r) * N + n] = acc[i][j][r];
            }
        }
    }
}

// ---------------------------------------------------------------------------
// Flash attention (causal), no-max softmax. Unchanged from R4 (verified):
// swapped QK^T (32x32x16), in-register P via pack+shfl_xor(32), K/V dbuf
// stage-early pipeline, by->t pairing, 64 KB LDS, 2 blocks/CU.
// ---------------------------------------------------------------------------
__global__ __launch_bounds__(256, 2) void attn_kernel(
    const bf16* __restrict__ qt, const bf16* __restrict__ kt,
    const bf16* __restrict__ vt, bf16* __restrict__ o) {
    __shared__ alignas(16) bf16 Ks[2][64 * 128];   // (row,sp): seg = sp ^ (row&15)
    __shared__ alignas(16) bf16 Vts[2][128 * 64];  // (row,sp): seg = sp ^ (row&7)

    const int tid = threadIdx.x;
    const int wave = tid >> 6, lane = tid & 63;
    const int l31 = lane & 31, h = lane >> 5;
    const int bh = blockIdx.x, by = blockIdx.y;
    const int t = by < 8 ? by : 23 - by;
    const int b_ = bh >> 4, hh = bh & 15;

    const int q0 = t * 128;
    const int qbase = q0 + wave * 32;
    const int qrow = qbase + l31;

    bf16x8 aq[8];
    {
        const bf16* qr = qt + (((size_t)bh * 2048 + qrow) << 7);
#pragma unroll
        for (int s = 0; s < 8; ++s)
            aq[s] = *(const bf16x8*)(qr + s * 16 + h * 8);
    }

    auto stageKV = [&](int buf, int k0) {
#pragma unroll
        for (int j = 0; j < 4; ++j) {
            const int c = tid + j * 256;
            const int row = c >> 4, sp = c & 15, s = sp ^ (row & 15);
            gload_lds16(kt + (((size_t)bh * 2048 + k0 + row) << 7) + s * 8,
                        &Ks[buf][c * 8]);
        }
#pragma unroll
        for (int j = 0; j < 4; ++j) {
            const int c = tid + j * 256;
            const int row = c >> 3, sp = c & 7, s = sp ^ (row & 7);
            gload_lds16(vt + ((size_t)bh * 128 + row) * 2048 + k0 + s * 8,
                        &Vts[buf][c * 8]);
        }
    };

    f32x16 oacc[4] = {};
    float lsum = 0.f;

    const int nit = 2 * t + 2;
    stageKV(0, 0);
    __syncthreads();
    int cur = 0;

    for (int it = 0; it < nit; ++it) {
        if (it + 1 < nit) stageKV(cur ^ 1, (it + 1) * 64);
        const int k0 = it * 64;

        if (k0 <= qbase + 31) {
            const bf16* Kc = &Ks[cur][0];
            const bf16* Vc = &Vts[cur][0];

            f32x16 sacc[2] = {};
            __builtin_amdgcn_s_setprio(1);
#pragma unroll
            for (int nt = 0; nt < 2; ++nt) {
#pragma unroll
                for (int s = 0; s < 8; ++s) {
                    const int sp = (2 * s + h) ^ (l31 & 15);
                    bf16x8 bk = *(const bf16x8*)(Kc + (nt * 32 + l31) * 128 + sp * 8);
                    sacc[nt] = MFMA32(bk, aq[s], sacc[nt]);
                }
            }
            __builtin_amdgcn_s_setprio(0);

            const bool needmask = (k0 + 63) > qbase;
            bf16x8 ap[4];
#pragma unroll
            for (int s4 = 0; s4 < 4; ++s4) {
                const int nt = s4 >> 1, base = (s4 & 1) * 8;
                float e[8];
#pragma unroll
                for (int k = 0; k < 8; ++k) {
                    const int c = base + k;
                    const int key = k0 + nt * 32 + (c & 3) + 8 * (c >> 2) + 4 * h;
                    float v = __expf(sacc[nt][c]);
                    if (needmask && key > qrow) v = 0.f;
                    e[k] = v;
                    lsum += v;
                }
                const int X0 = pack2(e[0], e[1]), X1 = pack2(e[2], e[3]);
                const int Y0 = pack2(e[4], e[5]), Y1 = pack2(e[6], e[7]);
                int W0 = h ? X0 : Y0, W1 = h ? X1 : Y1;
                W0 = __shfl_xor(W0, 32);
                W1 = __shfl_xor(W1, 32);
                union { intx4 w; bf16x8 v; } u;
                u.w[0] = h ? W0 : X0;
                u.w[1] = h ? W1 : X1;
                u.w[2] = h ? Y0 : W0;
                u.w[3] = h ? Y1 : W1;
                ap[s4] = u.v;
            }

            __builtin_amdgcn_s_setprio(1);
#pragma unroll
            for (int d0 = 0; d0 < 4; ++d0) {
#pragma unroll
                for (int ks = 0; ks < 4; ++ks) {
                    const int sp = (2 * ks + h) ^ (l31 & 7);
                    bf16x8 bv = *(const bf16x8*)(Vc + (d0 * 32 + l31) * 64 + sp * 8);
                    oacc[d0] = MFMA32(ap[ks], bv, oacc[d0]);
                }
            }
            __builtin_amdgcn_s_setprio(0);
        }

        __syncthreads();
        cur ^= 1;
    }

    lsum += __shfl_xor(lsum, 32);
    const float inv = 1.0f / lsum;
    float invr[16];
#pragma unroll
    for (int r = 0; r < 16; ++r)
        invr[r] = __shfl(inv, (r & 3) + 8 * (r >> 2) + 4 * h, 32);

#pragma unroll
    for (int d0 = 0; d0 < 4; ++d0) {
#pragma unroll
        for (int r = 0; r < 16; ++r) {
            const int rr = (r & 3) + 8 * (r >> 2) + 4 * h;
            o[(size_t)(b_ * 2048 + qbase + rr) * 2048 + hh * 128 + d0 * 32 + l31] =
                (bf16)(oacc[d0][r] * invr[r]);
        }
    }
}

// ---------------------------------------------------------------------------
extern "C" void kernel_launch(void* const* d_in, const int* in_sizes, int n_in,
                              void* d_out, int out_size, void* d_ws, size_t ws_size,
                              hipStream_t stream) {
    const float* x    = (const float*)d_in[0];  // [4096][2048] fp32
    const float* Wqkv = (const float*)d_in[1];  // [2048][6144] fp32
    const float* Wo   = (const float*)d_in[2];  // [2048][2048] fp32
    float* out        = (float*)d_out;          // [4096][2048] fp32

    char* ws = (char*)d_ws;
    bf16* xb    = (bf16*)ws; ws += (size_t)4096 * 2048 * 2;
    bf16* WqkvT = (bf16*)ws; ws += (size_t)6144 * 2048 * 2;
    bf16* WoT   = (bf16*)ws; ws += (size_t)2048 * 2048 * 2;
    bf16* qt    = (bf16*)ws; ws += (size_t)32 * 2048 * 128 * 2;
    bf16* kt    = (bf16*)ws; ws += (size_t)32 * 2048 * 128 * 2;
    bf16* vt    = (bf16*)ws; ws += (size_t)32 * 128 * 2048 * 2;
    bf16* ob    = (bf16*)ws; ws += (size_t)4096 * 2048 * 2;

    prep_kernel<<<24576, 256, 0, stream>>>(x, Wqkv, Wo, xb, WqkvT, WoT);

    gemm256_qkv_kernel<<<dim3(24, 16), 512, 0, stream>>>(
        xb, WqkvT, 2048, qt, kt, vt);

    attn_kernel<<<dim3(32, 16), 256, 0, stream>>>(qt, kt, vt, ob);

    gemm_bt_kernel<1><<<dim3(16, 32), 256, 0, stream>>>(
        ob, WoT, 4096, 2048, 2048, nullptr, nullptr, nullptr, out);
}

// Round 6
// 362.812 us; speedup vs baseline: 1.0678x; 1.0678x over previous
//
#include <hip/hip_runtime.h>
#include <hip/hip_bf16.h>
#include <cstdint>

typedef __bf16 bf16;
typedef __bf16 bf16x8 __attribute__((ext_vector_type(8)));
typedef __bf16 bf16x4 __attribute__((ext_vector_type(4)));
typedef __bf16 bf16x2 __attribute__((ext_vector_type(2)));
typedef float floatx4 __attribute__((ext_vector_type(4)));
typedef float f32x16 __attribute__((ext_vector_type(16)));
typedef int intx4 __attribute__((ext_vector_type(4)));

#define MFMA16(a, b, c) __builtin_amdgcn_mfma_f32_16x16x32_bf16(a, b, c, 0, 0, 0)
#define MFMA32(a, b, c) __builtin_amdgcn_mfma_f32_32x32x16_bf16(a, b, c, 0, 0, 0)

__device__ __forceinline__ void gload_lds16(const void* g, void* l) {
    __builtin_amdgcn_global_load_lds(
        (const __attribute__((address_space(1))) void*)g,
        (__attribute__((address_space(3))) void*)l, 16, 0, 0);
}

__device__ __forceinline__ int pack2(float a, float b) {
    union { bf16x2 v; int u; } z;
    z.v[0] = (bf16)a;
    z.v[1] = (bf16)b;
    return z.u;
}

// ---------------------------------------------------------------------------
// Fused prep (kept from R5: measured ~-20 us vs 3 separate launches).
//   blocks [0, 8192):      downcast x -> xb
//   blocks [8192, 20480):  transpose Wqkv [2048][6144] -> WqkvT
//   blocks [20480, 24576): transpose Wo   [2048][2048] -> WoT
// ---------------------------------------------------------------------------
__global__ __launch_bounds__(256) void prep_kernel(
    const float* __restrict__ x, const float* __restrict__ Wqkv,
    const float* __restrict__ Wo, bf16* __restrict__ xb,
    bf16* __restrict__ WqkvT, bf16* __restrict__ WoT) {
    __shared__ float tile[32][33];
    const int bid = blockIdx.x;
    const int tid = threadIdx.x;

    if (bid < 8192) {
        const size_t i = ((size_t)bid * 256 + tid) * 4;
        const float4 v = *(const float4*)(x + i);
        bf16x4 o = {(bf16)v.x, (bf16)v.y, (bf16)v.z, (bf16)v.w};
        *(bf16x4*)(xb + i) = o;
        return;
    }

    const float* in;
    bf16* out;
    int R, C, bx, by;
    if (bid < 20480) {
        const int b = bid - 8192;
        in = Wqkv; out = WqkvT; R = 2048; C = 6144;
        bx = b % 192; by = b / 192;
    } else {
        const int b = bid - 20480;
        in = Wo; out = WoT; R = 2048; C = 2048;
        bx = b & 63; by = b >> 6;
    }
    const int c0 = bx * 32, r0 = by * 32;
    const int tx = tid & 31, ty = tid >> 5;
    for (int i = 0; i < 32; i += 8)
        tile[ty + i][tx] = in[(size_t)(r0 + ty + i) * C + (c0 + tx)];
    __syncthreads();
    for (int i = 0; i < 32; i += 8)
        out[(size_t)(c0 + ty + i) * R + (r0 + tx)] = (bf16)tile[tx][ty + i];
}

// ---------------------------------------------------------------------------
// GEMM: C[M][N] = A[M][K] @ BT[N][K]^T   (bf16 in, fp32 accum)
// Verified 128x128 m97-structure (~117 us for qkv, 866 TF). Both R1 and R5
// 256^2 8-phase ports regressed (140/149 us, MfmaUtil 28) -> retired; this
// structure's ~900 TF is the session's qkv ceiling.
// MODE 0: epilogue scatters to q/k/v (N = 6144 = [3][16][128])
// MODE 1: epilogue writes FP32 C row-major [M][N]
// ---------------------------------------------------------------------------
template <int MODE>
__global__ __launch_bounds__(256) void gemm_bt_kernel(
    const bf16* __restrict__ A, const bf16* __restrict__ BT,
    int M, int N, int K,
    bf16* __restrict__ qt, bf16* __restrict__ kt, bf16* __restrict__ vt,
    float* __restrict__ Cout) {
    __shared__ alignas(16) bf16 As[128 * 64];  // 16 KB
    __shared__ alignas(16) bf16 Bs[128 * 64];  // 16 KB

    const int tid = threadIdx.x;
    const int wave = tid >> 6, lane = tid & 63;
    const int quad = lane >> 4, r16 = lane & 15;
    const int m0 = blockIdx.y * 128, n0 = blockIdx.x * 128;
    const int wm = (wave >> 1) * 64, wn = (wave & 1) * 64;

    // staging map: 4 chunks per matrix per thread; chunk c: row=c>>3, sp=c&7,
    // global seg s = sp ^ (row&7)
    int srow[4], soff[4];
#pragma unroll
    for (int j = 0; j < 4; ++j) {
        const int c = tid + j * 256;
        srow[j] = c >> 3;
        soff[j] = ((c & 7) ^ (srow[j] & 7)) * 8;
    }

    floatx4 acc[4][4] = {};

    for (int k0 = 0; k0 < K; k0 += 64) {
        __syncthreads();
#pragma unroll
        for (int j = 0; j < 4; ++j) {
            const int c = tid + j * 256;
            gload_lds16(A + (size_t)(m0 + srow[j]) * K + k0 + soff[j], As + c * 8);
            gload_lds16(BT + (size_t)(n0 + srow[j]) * K + k0 + soff[j], Bs + c * 8);
        }
        __syncthreads();

#pragma unroll
        for (int kc = 0; kc < 2; ++kc) {
            bf16x8 a[4], b[4];
#pragma unroll
            for (int i = 0; i < 4; ++i) {
                const int row = wm + i * 16 + r16;
                const int sp = (4 * kc + quad) ^ (row & 7);
                a[i] = *(const bf16x8*)(As + row * 64 + sp * 8);
            }
#pragma unroll
            for (int j = 0; j < 4; ++j) {
                const int row = wn + j * 16 + r16;
                const int sp = (4 * kc + quad) ^ (row & 7);
                b[j] = *(const bf16x8*)(Bs + row * 64 + sp * 8);
            }
#pragma unroll
            for (int i = 0; i < 4; ++i)
#pragma unroll
                for (int j = 0; j < 4; ++j)
                    acc[i][j] = MFMA16(a[i], b[j], acc[i][j]);
        }
    }

    if (MODE == 0) {
        const int t = n0 >> 11;  // block-uniform: which of q/k/v
        const float qscale = 0.08838834764831845f;  // 128^-0.5
#pragma unroll
        for (int i = 0; i < 4; ++i) {
            const int mbase = m0 + wm + i * 16 + quad * 4;
            const int b_ = mbase >> 11;
            const int s = mbase & 2047;
#pragma unroll
            for (int j = 0; j < 4; ++j) {
                const int n = n0 + wn + j * 16 + r16;
                const int h = (n >> 7) & 15, hd = n & 127;
                const int bh = b_ * 16 + h;
                if (t == 0) {
#pragma unroll
                    for (int r = 0; r < 4; ++r)
                        qt[(size_t)(bh * 2048 + s + r) * 128 + hd] =
                            (bf16)(acc[i][j][r] * qscale);
                } else if (t == 1) {
#pragma unroll
                    for (int r = 0; r < 4; ++r)
                        kt[(size_t)(bh * 2048 + s + r) * 128 + hd] = (bf16)acc[i][j][r];
                } else {
                    bf16x4 pv = {(bf16)acc[i][j][0], (bf16)acc[i][j][1],
                                 (bf16)acc[i][j][2], (bf16)acc[i][j][3]};
                    *(bf16x4*)(vt + (size_t)(bh * 128 + hd) * 2048 + s) = pv;
                }
            }
        }
    } else {
#pragma unroll
        for (int i = 0; i < 4; ++i) {
            const int mbase = m0 + wm + i * 16 + quad * 4;
#pragma unroll
            for (int j = 0; j < 4; ++j) {
                const int n = n0 + wn + j * 16 + r16;
#pragma unroll
                for (int r = 0; r < 4; ++r)
                    Cout[(size_t)(mbase + r) * N + n] = acc[i][j][r];
            }
        }
    }
}

// ---------------------------------------------------------------------------
// Flash attention (causal), no-max softmax. Unchanged from R4 (verified):
// swapped QK^T (32x32x16), in-register P via pack+shfl_xor(32), K/V dbuf
// stage-early pipeline, by->t pairing, 64 KB LDS, 2 blocks/CU.
// ---------------------------------------------------------------------------
__global__ __launch_bounds__(256, 2) void attn_kernel(
    const bf16* __restrict__ qt, const bf16* __restrict__ kt,
    const bf16* __restrict__ vt, bf16* __restrict__ o) {
    __shared__ alignas(16) bf16 Ks[2][64 * 128];   // (row,sp): seg = sp ^ (row&15)
    __shared__ alignas(16) bf16 Vts[2][128 * 64];  // (row,sp): seg = sp ^ (row&7)

    const int tid = threadIdx.x;
    const int wave = tid >> 6, lane = tid & 63;
    const int l31 = lane & 31, h = lane >> 5;
    const int bh = blockIdx.x, by = blockIdx.y;
    const int t = by < 8 ? by : 23 - by;
    const int b_ = bh >> 4, hh = bh & 15;

    const int q0 = t * 128;
    const int qbase = q0 + wave * 32;
    const int qrow = qbase + l31;

    bf16x8 aq[8];
    {
        const bf16* qr = qt + (((size_t)bh * 2048 + qrow) << 7);
#pragma unroll
        for (int s = 0; s < 8; ++s)
            aq[s] = *(const bf16x8*)(qr + s * 16 + h * 8);
    }

    auto stageKV = [&](int buf, int k0) {
#pragma unroll
        for (int j = 0; j < 4; ++j) {
            const int c = tid + j * 256;
            const int row = c >> 4, sp = c & 15, s = sp ^ (row & 15);
            gload_lds16(kt + (((size_t)bh * 2048 + k0 + row) << 7) + s * 8,
                        &Ks[buf][c * 8]);
        }
#pragma unroll
        for (int j = 0; j < 4; ++j) {
            const int c = tid + j * 256;
            const int row = c >> 3, sp = c & 7, s = sp ^ (row & 7);
            gload_lds16(vt + ((size_t)bh * 128 + row) * 2048 + k0 + s * 8,
                        &Vts[buf][c * 8]);
        }
    };

    f32x16 oacc[4] = {};
    float lsum = 0.f;

    const int nit = 2 * t + 2;
    stageKV(0, 0);
    __syncthreads();
    int cur = 0;

    for (int it = 0; it < nit; ++it) {
        if (it + 1 < nit) stageKV(cur ^ 1, (it + 1) * 64);
        const int k0 = it * 64;

        if (k0 <= qbase + 31) {
            const bf16* Kc = &Ks[cur][0];
            const bf16* Vc = &Vts[cur][0];

            f32x16 sacc[2] = {};
            __builtin_amdgcn_s_setprio(1);
#pragma unroll
            for (int nt = 0; nt < 2; ++nt) {
#pragma unroll
                for (int s = 0; s < 8; ++s) {
                    const int sp = (2 * s + h) ^ (l31 & 15);
                    bf16x8 bk = *(const bf16x8*)(Kc + (nt * 32 + l31) * 128 + sp * 8);
                    sacc[nt] = MFMA32(bk, aq[s], sacc[nt]);
                }
            }
            __builtin_amdgcn_s_setprio(0);

            const bool needmask = (k0 + 63) > qbase;
            bf16x8 ap[4];
#pragma unroll
            for (int s4 = 0; s4 < 4; ++s4) {
                const int nt = s4 >> 1, base = (s4 & 1) * 8;
                float e[8];
#pragma unroll
                for (int k = 0; k < 8; ++k) {
                    const int c = base + k;
                    const int key = k0 + nt * 32 + (c & 3) + 8 * (c >> 2) + 4 * h;
                    float v = __expf(sacc[nt][c]);
                    if (needmask && key > qrow) v = 0.f;
                    e[k] = v;
                    lsum += v;
                }
                const int X0 = pack2(e[0], e[1]), X1 = pack2(e[2], e[3]);
                const int Y0 = pack2(e[4], e[5]), Y1 = pack2(e[6], e[7]);
                int W0 = h ? X0 : Y0, W1 = h ? X1 : Y1;
                W0 = __shfl_xor(W0, 32);
                W1 = __shfl_xor(W1, 32);
                union { intx4 w; bf16x8 v; } u;
                u.w[0] = h ? W0 : X0;
                u.w[1] = h ? W1 : X1;
                u.w[2] = h ? Y0 : W0;
                u.w[3] = h ? Y1 : W1;
                ap[s4] = u.v;
            }

            __builtin_amdgcn_s_setprio(1);
#pragma unroll
            for (int d0 = 0; d0 < 4; ++d0) {
#pragma unroll
                for (int ks = 0; ks < 4; ++ks) {
                    const int sp = (2 * ks + h) ^ (l31 & 7);
                    bf16x8 bv = *(const bf16x8*)(Vc + (d0 * 32 + l31) * 64 + sp * 8);
                    oacc[d0] = MFMA32(ap[ks], bv, oacc[d0]);
                }
            }
            __builtin_amdgcn_s_setprio(0);
        }

        __syncthreads();
        cur ^= 1;
    }

    lsum += __shfl_xor(lsum, 32);
    const float inv = 1.0f / lsum;
    float invr[16];
#pragma unroll
    for (int r = 0; r < 16; ++r)
        invr[r] = __shfl(inv, (r & 3) + 8 * (r >> 2) + 4 * h, 32);

#pragma unroll
    for (int d0 = 0; d0 < 4; ++d0) {
#pragma unroll
        for (int r = 0; r < 16; ++r) {
            const int rr = (r & 3) + 8 * (r >> 2) + 4 * h;
            o[(size_t)(b_ * 2048 + qbase + rr) * 2048 + hh * 128 + d0 * 32 + l31] =
                (bf16)(oacc[d0][r] * invr[r]);
        }
    }
}

// ---------------------------------------------------------------------------
extern "C" void kernel_launch(void* const* d_in, const int* in_sizes, int n_in,
                              void* d_out, int out_size, void* d_ws, size_t ws_size,
                              hipStream_t stream) {
    const float* x    = (const float*)d_in[0];  // [4096][2048] fp32
    const float* Wqkv = (const float*)d_in[1];  // [2048][6144] fp32
    const float* Wo   = (const float*)d_in[2];  // [2048][2048] fp32
    float* out        = (float*)d_out;          // [4096][2048] fp32

    char* ws = (char*)d_ws;
    bf16* xb    = (bf16*)ws; ws += (size_t)4096 * 2048 * 2;
    bf16* WqkvT = (bf16*)ws; ws += (size_t)6144 * 2048 * 2;
    bf16* WoT   = (bf16*)ws; ws += (size_t)2048 * 2048 * 2;
    bf16* qt    = (bf16*)ws; ws += (size_t)32 * 2048 * 128 * 2;
    bf16* kt    = (bf16*)ws; ws += (size_t)32 * 2048 * 128 * 2;
    bf16* vt    = (bf16*)ws; ws += (size_t)32 * 128 * 2048 * 2;
    bf16* ob    = (bf16*)ws; ws += (size_t)4096 * 2048 * 2;

    prep_kernel<<<24576, 256, 0, stream>>>(x, Wqkv, Wo, xb, WqkvT, WoT);

    gemm_bt_kernel<0><<<dim3(48, 32), 256, 0, stream>>>(
        xb, WqkvT, 4096, 6144, 2048, qt, kt, vt, nullptr);

    attn_kernel<<<dim3(32, 16), 256, 0, stream>>>(qt, kt, vt, ob);

    gemm_bt_kernel<1><<<dim3(16, 32), 256, 0, stream>>>(
        ob, WoT, 4096, 2048, 2048, nullptr, nullptr, nullptr, out);
}